// Round 11
// baseline (256.229 us; speedup 1.0000x reference)
//
#include <hip/hip_runtime.h>
#include <math.h>

// ---------------------------------------------------------------------------
// H=W=512, CELL=8, P=16, NGH=32; 4096 patches of 16x16, one block per patch.
// conv1 3x3 1->40 fp32 VALU; conv2 3x3 40->40 bf16 MFMA; dense1 from acc regs.
//
// R10 post-mortem: no spill (VGPR 56, WRITE 320 KB) but still 2 blocks/CU:
// 56 VGPR + ~32 AGPR (unified file) = 88 > 512/6 = 85 -> the 3rd block
// (6 waves/EU) misses by ~3 regs. R9 proved (512,6) does yield 3 blocks /
// 60% occupancy; it spilled only because the tail DOUBLE-buffer made the
// live set ~105. R11 = R10 + __launch_bounds__(512,6): single-buffered
// live set ~80 <= 85, so the allocator should fit without spilling.
// Tripwire: WRITE_SIZE >> 1 MB = spill -> revert to (512,4).
// R2 lesson: every register-array access constant-indexed.
// MFMA layouts (HW-verified): A[m=lane&15][k=quad*8+j]; B[k=quad*8+j][n=lane&15];
// C/D col(n)=lane&15, row(m)=quad*4+reg.
// ---------------------------------------------------------------------------

typedef __attribute__((ext_vector_type(8))) short short8;
typedef __attribute__((ext_vector_type(4))) float f32x4;

#define ZCELL 288                    // shared all-zero cell (after 16x18 grid)
#define NWTB  (12 * 4 * 48 * 8)      // 18432 shorts: B image [grp][quad][co:48][j:8]
#define NMAIN (9 * 4 * 48 * 8)       // 13824 shorts: main groups (staged to LDS)
#define ND1W  (256 * 48 * 8)         // 98304 shorts: dense1 bf16 [pixel][co:48][k:8]

static __device__ __forceinline__ unsigned short f2bf(float x) {
    unsigned int u = __float_as_uint(x);
    u += 0x7FFF + ((u >> 16) & 1);
    return (unsigned short)(u >> 16);
}

static __device__ __forceinline__ float diff_round(float x) {
    const float TP = 6.2831853071795864769f;
    return x - sinf(x * TP) / TP;
}

template<int IN, int OUT>
static __device__ __forceinline__ void mlp_layer(const float* in,
                                                 const float* __restrict__ w,
                                                 const float* __restrict__ b,
                                                 float* out, bool do_relu) {
#pragma unroll
    for (int j = 0; j < OUT; ++j) {
        float a = b[j];
#pragma unroll
        for (int i = 0; i < IN; ++i) a = fmaf(in[i], w[i * OUT + j], a);
        out[j] = do_relu ? fmaxf(a, 0.f) : a;
    }
}

// ---------------------------------------------------------------------------
// Prep: (a) wTbG = B-weight image in k_patch layout:
//   idx = ((grp*4+quad)*48 + co)*8 + j
//   grp<9 : tap=grp,      ci=quad*8+j   (main K-step, ci 0..31)
//   grp>=9: tap=(grp-9)*4+quad, ci=32+j (tail-packed; tap>=9 -> 0)
// (b) d1wb = dense1 weights bf16, [pixel][co:48][k:8] (k>=6 or co>=40 -> 0).
// ---------------------------------------------------------------------------
__global__ __launch_bounds__(256) void k_prep(const float* __restrict__ w2,
                                              const float* __restrict__ d1w,
                                              unsigned short* __restrict__ wTbG,
                                              unsigned short* __restrict__ d1wb) {
    const int i = blockIdx.x * 256 + threadIdx.x;
    if (i < NWTB) {
        const int j    = i & 7;
        const int co   = (i >> 3) % 48;
        const int qg   = (i >> 3) / 48;
        const int quad = qg & 3;
        const int grp  = qg >> 2;
        float val = 0.f;
        if (grp < 9) {
            if (co < 40) val = w2[(grp * 40 + quad * 8 + j) * 40 + co];
        } else {
            const int tap = (grp - 9) * 4 + quad;
            if (tap < 9 && co < 40) val = w2[(tap * 40 + 32 + j) * 40 + co];
        }
        wTbG[i] = f2bf(val);
    } else if (i < NWTB + ND1W) {
        const int jj = i - NWTB;
        const int k  = jj & 7;
        const int co = (jj >> 3) % 48;
        const int px = (jj >> 3) / 48;
        d1wb[jj] = f2bf((co < 40 && k < 6) ? d1w[(px * 40 + co) * 6 + k] : 0.f);
    }
}

// ---------------------------------------------------------------------------
// Kernel 1: 512 threads/block, one block per patch.
// ph = t>>8 (conv1 channel half), pix = t&255, u=pix>>4, v=pix&15.
// Wave wv (0..7) owns pixel rows wv*2, wv*2+1 in the MFMA phase.
// x1 cells: image row u (0..15) x col c (0..17) -> cell u*18+c; ZCELL=288.
// Conv2 A-read row r = wv*2+mt+ky in [0,17]: r==0/17 -> ZCELL, else row r-1.
// ---------------------------------------------------------------------------
__global__ __launch_bounds__(512, 6) void k_patch(
    const float* __restrict__ img, const float* __restrict__ lab,
    const float* __restrict__ msk,
    const float* __restrict__ w1, const float* __restrict__ b1,
    const unsigned short* __restrict__ wTbG,
    const float* __restrict__ b2,
    const unsigned short* __restrict__ d1wb, const float* __restrict__ d1b,
    float* __restrict__ nodes, float* __restrict__ lsv)
{
    __shared__ __align__(16) unsigned short x1[289 * 40];   // 23,120 B
    __shared__ __align__(16) unsigned short Bs[NMAIN];      // 27,648 B
    __shared__ float p[256];
    __shared__ float red[4][2];
    __shared__ float wsum[8][6];

    const int n = blockIdx.x;
    const int t = threadIdx.x;
    const int g = n >> 10, cell = n & 1023;
    const int gi = cell >> 5, gj = cell & 31;
    const int sx = g & 1, sy = g >> 1;           // SHIFTS (0,0),(1,0),(0,1),(1,1)
    const int gx = sx + 2 * gi, gy = sy + 2 * gj;
    const int px0 = gx * 8 - 4, py0 = gy * 8 - 4;
    const float cid = (float)(gx * 64 + gy);

    const int ph = t >> 8, pix = t & 255;
    const int u = pix >> 4, v = pix & 15;
    const int lane = t & 63, wv = t >> 6;
    const int lane15 = t & 15, quad = (t >> 4) & 3;

    // ---- entry: issue patch global loads (ph==0 half) ----
    float m = -1.f, iv = 0.f, lv = 0.f;
    if (ph == 0) {
        const int r = px0 + u, c = py0 + v;
        if (r >= 0 && r < 512 && c >= 0 && c < 512) {
            m  = msk[r * 512 + c];
            iv = img[r * 512 + c];
            lv = lab[r * 512 + c];
        }
    }

    // ---- stage main B-groups into LDS (flat copy, layout matches) ----
    {
        const uint4* src = (const uint4*)wTbG;
        uint4* dst = (uint4*)Bs;
        for (int i = t; i < NMAIN / 8; i += 512) dst[i] = src[i];
    }

    // ---- zero x1 border cols + ZCELL (33 cells * 20 dwords = 660) ----
    {
        unsigned int* x1w = (unsigned int*)x1;
        for (int i = t; i < 33 * 20; i += 512) {
            const int cI = i / 20, d = i - cI * 20;
            int cr;
            if      (cI < 16) cr = cI * 18;             // col 0, rows 0..15
            else if (cI < 32) cr = (cI - 16) * 18 + 17; // col 17
            else              cr = ZCELL;
            x1w[cr * 20 + d] = 0u;
        }
    }

    // ---- token + label stats (ph==0 waves) ----
    const float f = (m == cid) ? 1.f : 0.f;
    if (ph == 0) {
        p[pix] = iv * f;
        float sf = f, slf = lv * f;
        for (int off = 32; off; off >>= 1) {
            sf  += __shfl_down(sf,  off);
            slf += __shfl_down(slf, off);
        }
        if (lane == 0) { red[wv][0] = sf; red[wv][1] = slf; }
    }
    __syncthreads();                                   // B1

    if (t == 0) {
        const float SF = red[0][0] + red[1][0] + red[2][0] + red[3][0];
        const float SL = red[0][1] + red[1][1] + red[2][1] + red[3][1];
        lsv[n] = diff_round(diff_round(SL / (SF + 1e-8f)));
    }

    // ---- conv1: each thread: its pixel x its 20-channel half ----
    {
        float nbv[9];
#pragma unroll
        for (int ky = 0; ky < 3; ++ky)
#pragma unroll
            for (int kx = 0; kx < 3; ++kx) {
                const int uy = u + ky - 1, vx = v + kx - 1;
                const bool ok = (uy >= 0) && (uy < 16) && (vx >= 0) && (vx < 16);
                nbv[ky * 3 + kx] = ok ? p[uy * 16 + vx] : 0.f;
            }
        float a1[20];
#pragma unroll
        for (int cc = 0; cc < 20; ++cc) a1[cc] = b1[ph * 20 + cc];
#pragma unroll
        for (int k = 0; k < 9; ++k) {
            const float xv = nbv[k];
#pragma unroll
            for (int cc = 0; cc < 20; ++cc)
                a1[cc] = fmaf(xv, w1[k * 40 + ph * 20 + cc], a1[cc]);
        }
        const int wcell = u * 18 + (v + 1);            // row u, col v+1
        unsigned int* x1w = (unsigned int*)x1;
#pragma unroll
        for (int cg = 0; cg < 10; ++cg) {
            const unsigned int lo = f2bf(fmaxf(a1[2 * cg], 0.f));
            const unsigned int hi = f2bf(fmaxf(a1[2 * cg + 1], 0.f));
            x1w[wcell * 20 + ph * 10 + cg] = lo | (hi << 16);
        }
    }
    __syncthreads();                                   // B2: x1 + Bs ready

    // ---- conv2: 9 main (LDS B) + 3 tail-packed (global B, single-buf) ----
    float bias[3];
#pragma unroll
    for (int nt = 0; nt < 3; ++nt) {
        const int co = nt * 16 + lane15;
        bias[nt] = (co < 40) ? b2[co] : 0.f;
    }
    f32x4 acc[2][3];
#pragma unroll
    for (int mt = 0; mt < 2; ++mt)
#pragma unroll
        for (int nt = 0; nt < 3; ++nt) {
            acc[mt][nt][0] = bias[nt]; acc[mt][nt][1] = bias[nt];
            acc[mt][nt][2] = bias[nt]; acc[mt][nt][3] = bias[nt];
        }

#pragma unroll
    for (int tap = 0; tap < 9; ++tap) {
        const int ky = tap / 3, kx = tap % 3;
        short8 bf[3];
#pragma unroll
        for (int nt = 0; nt < 3; ++nt)
            bf[nt] = *(const short8*)(Bs + ((tap * 4 + quad) * 48 + nt * 16 + lane15) * 8);
#pragma unroll
        for (int mt = 0; mt < 2; ++mt) {
            const int r = wv * 2 + mt + ky;            // 0..17
            const int acell = (r == 0 || r == 17) ? ZCELL
                              : ((r - 1) * 18 + lane15 + kx);
            const short8 a0 = *(const short8*)(x1 + acell * 40 + quad * 8);
#pragma unroll
            for (int nt = 0; nt < 3; ++nt)
                acc[mt][nt] = __builtin_amdgcn_mfma_f32_16x16x32_bf16(
                    a0, bf[nt], acc[mt][nt], 0, 0, 0);
        }
    }
#pragma unroll
    for (int s = 0; s < 3; ++s) {
        // single-buffered tail B from L2 (36 KB image, L2-resident);
        // latency amortized over 18 MFMAs per s-iteration + wave overlap.
        short8 btc[3];
#pragma unroll
        for (int nt = 0; nt < 3; ++nt)
            btc[nt] = *(const short8*)(wTbG +
                (((9 + s) * 4 + quad) * 48 + nt * 16 + lane15) * 8);
        const int tapq = s * 4 + quad;
        const int kyq  = (tapq * 11) >> 5;             // tapq/3 for 0..11
        const int kxq  = tapq - 3 * kyq;
#pragma unroll
        for (int mt = 0; mt < 2; ++mt) {
            const int rq = wv * 2 + mt + kyq;
            const bool zq = (tapq >= 9) || (rq == 0) || (rq == 17);
            const int cellq = zq ? ZCELL : ((rq - 1) * 18 + lane15 + kxq);
            const short8 at = *(const short8*)(x1 + cellq * 40 + 32);
#pragma unroll
            for (int nt = 0; nt < 3; ++nt)
                acc[mt][nt] = __builtin_amdgcn_mfma_f32_16x16x32_bf16(
                    at, btc[nt], acc[mt][nt], 0, 0, 0);
        }
    }

    // ---- dense1 straight from accumulators; bf16 weights, 1 uint4/segment --
    float a6[6] = {0.f, 0.f, 0.f, 0.f, 0.f, 0.f};
#pragma unroll
    for (int mt = 0; mt < 2; ++mt)
#pragma unroll
        for (int nt = 0; nt < 3; ++nt) {
            const int co = nt * 16 + lane15;
#pragma unroll
            for (int reg = 0; reg < 4; ++reg) {
                const int pixel = (wv * 2 + mt) * 16 + quad * 4 + reg;
                const uint4 wq = *(const uint4*)(d1wb + ((pixel * 48 + co) << 3));
                const float a = fmaxf(acc[mt][nt][reg], 0.f);
                a6[0] = fmaf(a, __uint_as_float(wq.x << 16),          a6[0]);
                a6[1] = fmaf(a, __uint_as_float(wq.x & 0xFFFF0000u),  a6[1]);
                a6[2] = fmaf(a, __uint_as_float(wq.y << 16),          a6[2]);
                a6[3] = fmaf(a, __uint_as_float(wq.y & 0xFFFF0000u),  a6[3]);
                a6[4] = fmaf(a, __uint_as_float(wq.z << 16),          a6[4]);
                a6[5] = fmaf(a, __uint_as_float(wq.z & 0xFFFF0000u),  a6[5]);
            }
        }
    for (int off = 32; off; off >>= 1) {
#pragma unroll
        for (int k = 0; k < 6; ++k) a6[k] += __shfl_down(a6[k], off);
    }
    if (lane == 0) {
#pragma unroll
        for (int k = 0; k < 6; ++k) wsum[wv][k] = a6[k];
    }
    __syncthreads();                                   // B3
    if (t < 6) {
        float s = d1b[t];
#pragma unroll
        for (int w = 0; w < 8; ++w) s += wsum[w][t];
        nodes[n * 6 + t] = fmaxf(s, 0.f);
    }
}

// ---------------------------------------------------------------------------
// Kernel 2: per-node fused edge-MLPs (<=4 incoming, analytic grid adjacency)
// + node MLP + softmax CE.
// node_id(x,y) = ((x&1)+2*(y&1))*1024 + (x>>1)*32 + (y>>1).
// ---------------------------------------------------------------------------
__global__ __launch_bounds__(64) void k_node(
    const float* __restrict__ nodes, const float* __restrict__ lsv,
    const float* __restrict__ we0, const float* __restrict__ be0,
    const float* __restrict__ we1, const float* __restrict__ be1,
    const float* __restrict__ we2, const float* __restrict__ be2,
    const float* __restrict__ we3, const float* __restrict__ be3,
    const float* __restrict__ wn0, const float* __restrict__ bn0,
    const float* __restrict__ wn1, const float* __restrict__ bn1,
    const float* __restrict__ wn2, const float* __restrict__ bn2,
    const float* __restrict__ wn3, const float* __restrict__ bn3,
    const float* __restrict__ wout, const float* __restrict__ bout,
    float* __restrict__ out, int N)
{
    const int n = blockIdx.x * 64 + threadIdx.x;
    if (n >= N) return;
    const int g = n >> 10, cell = n & 1023;
    const int gi = cell >> 5, gj = cell & 31;
    const int gx = (g & 1) + 2 * gi, gy = (g >> 1) + 2 * gj;

    float self6[6];
#pragma unroll
    for (int i = 0; i < 6; ++i) self6[i] = nodes[n * 6 + i];

    float agg[10] = {0.f,0.f,0.f,0.f,0.f,0.f,0.f,0.f,0.f,0.f};
    const int DX[4] = {0, 0, -1, 1};
    const int DY[4] = {-1, 1, 0, 0};
#pragma unroll
    for (int d = 0; d < 4; ++d) {
        const int x = gx + DX[d], y = gy + DY[d];
        if (x >= 0 && x < 64 && y >= 0 && y < 64) {
            const int mid = ((x & 1) + 2 * (y & 1)) * 1024 + (x >> 1) * 32 + (y >> 1);
            float in13[13];
#pragma unroll
            for (int i = 0; i < 6; ++i) in13[i] = nodes[mid * 6 + i];
#pragma unroll
            for (int i = 0; i < 6; ++i) in13[6 + i] = self6[i];
            in13[12] = 1.f;
            float h0[5], h1[5], h2[5], o[10];
            mlp_layer<13, 5>(in13, we0, be0, h0, true);
            mlp_layer<5, 5>(h0, we1, be1, h1, true);
            mlp_layer<5, 5>(h1, we2, be2, h2, true);
            mlp_layer<5, 10>(h2, we3, be3, o, false);
#pragma unroll
            for (int j = 0; j < 10; ++j) agg[j] += o[j];
        }
    }

    float in17[17];
#pragma unroll
    for (int i = 0; i < 6; ++i)  in17[i]     = self6[i];
#pragma unroll
    for (int i = 0; i < 10; ++i) in17[6 + i] = agg[i];
    in17[16] = 1.f;
    float h0[5], h1[5], h2[5], o[10];
    mlp_layer<17, 5>(in17, wn0, bn0, h0, true);
    mlp_layer<5, 5>(h0, wn1, bn1, h1, true);
    mlp_layer<5, 5>(h1, wn2, bn2, h2, true);
    mlp_layer<5, 10>(h2, wn3, bn3, o, false);

    float l0 = bout[0], l1 = bout[1];
#pragma unroll
    for (int i = 0; i < 10; ++i) {
        l0 = fmaf(o[i], wout[i * 2 + 0], l0);
        l1 = fmaf(o[i], wout[i * 2 + 1], l1);
    }
    const float mx  = fmaxf(l0, l1);
    const float e0  = expf(l0 - mx), e1 = expf(l1 - mx);
    const float lse = mx + logf(e0 + e1);
    const float sv  = lsv[n];
    out[n] = -((1.f - sv) * (l0 - lse) + sv * (l1 - lse));
}

// ---------------------------------------------------------------------------
extern "C" void kernel_launch(void* const* d_in, const int* in_sizes, int n_in,
                              void* d_out, int out_size, void* d_ws, size_t ws_size,
                              hipStream_t stream) {
    (void)n_in; (void)ws_size; (void)in_sizes;
    const float* img = (const float*)d_in[0];
    const float* lab = (const float*)d_in[1];
    const float* msk = (const float*)d_in[2];
    const float* w1  = (const float*)d_in[3];
    const float* b1  = (const float*)d_in[4];
    const float* w2  = (const float*)d_in[5];
    const float* b2  = (const float*)d_in[6];
    const float* d1w = (const float*)d_in[7];
    const float* d1b = (const float*)d_in[8];
    const float* we0 = (const float*)d_in[9],  *be0 = (const float*)d_in[10];
    const float* we1 = (const float*)d_in[11], *be1 = (const float*)d_in[12];
    const float* we2 = (const float*)d_in[13], *be2 = (const float*)d_in[14];
    const float* we3 = (const float*)d_in[15], *be3 = (const float*)d_in[16];
    const float* wn0 = (const float*)d_in[17], *bn0 = (const float*)d_in[18];
    const float* wn1 = (const float*)d_in[19], *bn1 = (const float*)d_in[20];
    const float* wn2 = (const float*)d_in[21], *bn2 = (const float*)d_in[22];
    const float* wn3 = (const float*)d_in[23], *bn3 = (const float*)d_in[24];
    const float* wout = (const float*)d_in[25], *bout = (const float*)d_in[26];
    const int N = out_size;              // 4096 nodes

    char* base = (char*)d_ws;
    float* nodes = (float*)base;                             // N*6 floats
    float* lsvb  = (float*)(base + (size_t)N * 6 * 4);       // N floats
    unsigned short* wTbG = (unsigned short*)(base + (size_t)N * 7 * 4);  // 18432
    unsigned short* d1wb = wTbG + NWTB;                      // 98304
    float* out   = (float*)d_out;

    const int prep_n = NWTB + ND1W;
    k_prep<<<(prep_n + 255) / 256, 256, 0, stream>>>(w2, d1w, wTbG, d1wb);
    k_patch<<<N, 512, 0, stream>>>(img, lab, msk, w1, b1, wTbG, b2,
                                   d1wb, d1b, nodes, lsvb);
    k_node<<<(N + 63) / 64, 64, 0, stream>>>(nodes, lsvb,
                                             we0, be0, we1, be1, we2, be2,
                                             we3, be3,
                                             wn0, bn0, wn1, bn1, wn2, bn2,
                                             wn3, bn3, wout, bout, out, N);
}

// Round 12
// 219.120 us; speedup vs baseline: 1.1694x; 1.1694x over previous
//
#include <hip/hip_runtime.h>
#include <math.h>

// ---------------------------------------------------------------------------
// H=W=512, CELL=8, P=16, NGH=32; 4096 patches of 16x16, one block per patch.
// conv1 3x3 1->40 fp32 VALU; conv2 3x3 40->40 bf16 MFMA; dense1 from acc regs.
//
// R11 post-mortem: (512,6) spilled AGAIN (VGPR 40, WRITE 128 MB) -> the
// ~88-reg live set cannot fit an 85-reg budget; occupancy is capped at
// 2 blocks/CU for this structure (proven R9+R11). R10's tail-from-L2 +
// ZCELL select also cost ~6 us vs R8 at equal occupancy. R12 therefore
// reverts to the best-measured R8 config (full B in LDS, x1 325 rows,
// (512,4), 64.5 KB LDS) with ONE change: the Bs staging is moved to after
// barrier B1, so its vmcnt drain (forced by __syncthreads, which always
// waits vmcnt(0)) lands at B2 with conv1's ~360 issue-cycles in between,
// instead of stalling undefended at B1.
// Lessons: never pin launch-bounds below live set (R5/R9/R11); every
// register-array access constant-indexed (R2).
// MFMA layouts (HW-verified): A[m=lane&15][k=quad*8+j]; B[k=quad*8+j][n=lane&15];
// C/D col(n)=lane&15, row(m)=quad*4+reg.
// ---------------------------------------------------------------------------

typedef __attribute__((ext_vector_type(8))) short short8;
typedef __attribute__((ext_vector_type(4))) float f32x4;

#define ZROW  324                    // always-zero x1 row (rows 0..323 = 18x18)
#define NWTB  (12 * 4 * 48 * 8)      // 18432 shorts: B image [grp][quad][co:48][j:8]
#define ND1W  (256 * 48 * 8)         // 98304 shorts: dense1 bf16 [pixel][co:48][k:8]

static __device__ __forceinline__ unsigned short f2bf(float x) {
    unsigned int u = __float_as_uint(x);
    u += 0x7FFF + ((u >> 16) & 1);
    return (unsigned short)(u >> 16);
}

static __device__ __forceinline__ float diff_round(float x) {
    const float TP = 6.2831853071795864769f;
    return x - sinf(x * TP) / TP;
}

template<int IN, int OUT>
static __device__ __forceinline__ void mlp_layer(const float* in,
                                                 const float* __restrict__ w,
                                                 const float* __restrict__ b,
                                                 float* out, bool do_relu) {
#pragma unroll
    for (int j = 0; j < OUT; ++j) {
        float a = b[j];
#pragma unroll
        for (int i = 0; i < IN; ++i) a = fmaf(in[i], w[i * OUT + j], a);
        out[j] = do_relu ? fmaxf(a, 0.f) : a;
    }
}

// ---------------------------------------------------------------------------
// Prep: (a) wTbG = B-weight image in EXACTLY the k_patch LDS layout:
//   idx = ((grp*4+quad)*48 + co)*8 + j
//   grp<9 : tap=grp,      ci=quad*8+j   (main K-step, ci 0..31)
//   grp>=9: tap=(grp-9)*4+quad, ci=32+j (tail-packed K-step; tap>=9 -> 0)
// (b) d1wb = dense1 weights bf16, [pixel][co:48][k:8] (k>=6 or co>=40 -> 0).
// ---------------------------------------------------------------------------
__global__ __launch_bounds__(256) void k_prep(const float* __restrict__ w2,
                                              const float* __restrict__ d1w,
                                              unsigned short* __restrict__ wTbG,
                                              unsigned short* __restrict__ d1wb) {
    const int i = blockIdx.x * 256 + threadIdx.x;
    if (i < NWTB) {
        const int j    = i & 7;
        const int co   = (i >> 3) % 48;
        const int qg   = (i >> 3) / 48;
        const int quad = qg & 3;
        const int grp  = qg >> 2;
        float val = 0.f;
        if (grp < 9) {
            if (co < 40) val = w2[(grp * 40 + quad * 8 + j) * 40 + co];
        } else {
            const int tap = (grp - 9) * 4 + quad;
            if (tap < 9 && co < 40) val = w2[(tap * 40 + 32 + j) * 40 + co];
        }
        wTbG[i] = f2bf(val);
    } else if (i < NWTB + ND1W) {
        const int jj = i - NWTB;
        const int k  = jj & 7;
        const int co = (jj >> 3) % 48;
        const int px = (jj >> 3) / 48;
        d1wb[jj] = f2bf((co < 40 && k < 6) ? d1w[(px * 40 + co) * 6 + k] : 0.f);
    }
}

// ---------------------------------------------------------------------------
// Kernel 1: 512 threads/block, one block per patch.
// ph = t>>8 (conv1 channel half), pix = t&255, u=pix>>4, v=pix&15.
// Wave wv (0..7) owns pixel rows wv*2, wv*2+1 in the MFMA phase.
// ---------------------------------------------------------------------------
__global__ __launch_bounds__(512, 4) void k_patch(
    const float* __restrict__ img, const float* __restrict__ lab,
    const float* __restrict__ msk,
    const float* __restrict__ w1, const float* __restrict__ b1,
    const unsigned short* __restrict__ wTbG,
    const float* __restrict__ b2,
    const unsigned short* __restrict__ d1wb, const float* __restrict__ d1b,
    float* __restrict__ nodes, float* __restrict__ lsv)
{
    __shared__ __align__(16) unsigned short x1[325 * 40];   // 26,000 B
    __shared__ __align__(16) unsigned short Bs[NWTB];       // 36,864 B
    __shared__ float p[256];
    __shared__ float red[4][2];
    __shared__ float wsum[8][6];

    const int n = blockIdx.x;
    const int t = threadIdx.x;
    const int g = n >> 10, cell = n & 1023;
    const int gi = cell >> 5, gj = cell & 31;
    const int sx = g & 1, sy = g >> 1;           // SHIFTS (0,0),(1,0),(0,1),(1,1)
    const int gx = sx + 2 * gi, gy = sy + 2 * gj;
    const int px0 = gx * 8 - 4, py0 = gy * 8 - 4;
    const float cid = (float)(gx * 64 + gy);

    const int ph = t >> 8, pix = t & 255;
    const int u = pix >> 4, v = pix & 15;
    const int lane = t & 63, wv = t >> 6;
    const int lane15 = t & 15, quad = (t >> 4) & 3;

    // ---- entry: issue patch global loads (ph==0 half) ----
    float m = -1.f, iv = 0.f, lv = 0.f;
    if (ph == 0) {
        const int r = px0 + u, c = py0 + v;
        if (r >= 0 && r < 512 && c >= 0 && c < 512) {
            m  = msk[r * 512 + c];
            iv = img[r * 512 + c];
            lv = lab[r * 512 + c];
        }
    }

    // ---- zero x1 borders + ZROW (69 cells * 20 dwords) ----
    {
        unsigned int* x1w = (unsigned int*)x1;
        for (int i = t; i < 69 * 20; i += 512) {
            const int cellI = i / 20, d = i - cellI * 20;
            int cr;
            if      (cellI < 18) cr = cellI;                    // row 0
            else if (cellI < 36) cr = cellI + 288;              // row 17
            else if (cellI < 52) cr = (cellI - 35) * 18;        // col 0, rows 1..16
            else if (cellI < 68) cr = (cellI - 51) * 18 + 17;   // col 17
            else                 cr = ZROW;
            x1w[cr * 20 + d] = 0u;
        }
    }

    // ---- token + label stats (ph==0 waves) ----
    const float f = (m == cid) ? 1.f : 0.f;
    if (ph == 0) {
        p[pix] = iv * f;
        float sf = f, slf = lv * f;
        for (int off = 32; off; off >>= 1) {
            sf  += __shfl_down(sf,  off);
            slf += __shfl_down(slf, off);
        }
        if (lane == 0) { red[wv][0] = sf; red[wv][1] = slf; }
    }
    __syncthreads();                                   // B1

    if (t == 0) {
        const float SF = red[0][0] + red[1][0] + red[2][0] + red[3][0];
        const float SL = red[0][1] + red[1][1] + red[2][1] + red[3][1];
        lsv[n] = diff_round(diff_round(SL / (SF + 1e-8f)));
    }

    // ---- stage B-weights into LDS (moved AFTER B1): the __syncthreads
    // vmcnt(0) drain for these loads now lands at B2, with conv1's ~360
    // issue-cycles between load-issue and drain instead of stalling at B1.
    {
        const uint4* src = (const uint4*)wTbG;
        uint4* dst = (uint4*)Bs;
        for (int i = t; i < NWTB / 8; i += 512) dst[i] = src[i];
    }

    // ---- conv1: each thread: its pixel x its 20-channel half ----
    {
        float nbv[9];
#pragma unroll
        for (int ky = 0; ky < 3; ++ky)
#pragma unroll
            for (int kx = 0; kx < 3; ++kx) {
                const int uy = u + ky - 1, vx = v + kx - 1;
                const bool ok = (uy >= 0) && (uy < 16) && (vx >= 0) && (vx < 16);
                nbv[ky * 3 + kx] = ok ? p[uy * 16 + vx] : 0.f;
            }
        float a1[20];
#pragma unroll
        for (int cc = 0; cc < 20; ++cc) a1[cc] = b1[ph * 20 + cc];
#pragma unroll
        for (int k = 0; k < 9; ++k) {
            const float xv = nbv[k];
#pragma unroll
            for (int cc = 0; cc < 20; ++cc)
                a1[cc] = fmaf(xv, w1[k * 40 + ph * 20 + cc], a1[cc]);
        }
        const int row = (u + 1) * 18 + (v + 1);
        unsigned int* x1w = (unsigned int*)x1;
#pragma unroll
        for (int cg = 0; cg < 10; ++cg) {
            const unsigned int lo = f2bf(fmaxf(a1[2 * cg], 0.f));
            const unsigned int hi = f2bf(fmaxf(a1[2 * cg + 1], 0.f));
            x1w[row * 20 + ph * 10 + cg] = lo | (hi << 16);
        }
    }
    __syncthreads();                                   // B2: x1 + Bs ready

    // ---- conv2: 9 main + 3 tail-packed K-steps, all operands from LDS ----
    float bias[3];
#pragma unroll
    for (int nt = 0; nt < 3; ++nt) {
        const int co = nt * 16 + lane15;
        bias[nt] = (co < 40) ? b2[co] : 0.f;
    }
    f32x4 acc[2][3];
#pragma unroll
    for (int mt = 0; mt < 2; ++mt)
#pragma unroll
        for (int nt = 0; nt < 3; ++nt) {
            acc[mt][nt][0] = bias[nt]; acc[mt][nt][1] = bias[nt];
            acc[mt][nt][2] = bias[nt]; acc[mt][nt][3] = bias[nt];
        }

#pragma unroll
    for (int tap = 0; tap < 9; ++tap) {
        const int ky = tap / 3, kx = tap % 3;
        short8 bf[3];
#pragma unroll
        for (int nt = 0; nt < 3; ++nt)
            bf[nt] = *(const short8*)(Bs + ((tap * 4 + quad) * 48 + nt * 16 + lane15) * 8);
#pragma unroll
        for (int mt = 0; mt < 2; ++mt) {
            const int arow = (wv * 2 + mt + ky) * 18 + (lane15 + kx);
            const short8 a0 = *(const short8*)(x1 + arow * 40 + quad * 8);
#pragma unroll
            for (int nt = 0; nt < 3; ++nt)
                acc[mt][nt] = __builtin_amdgcn_mfma_f32_16x16x32_bf16(
                    a0, bf[nt], acc[mt][nt], 0, 0, 0);
        }
    }
#pragma unroll
    for (int s = 0; s < 3; ++s) {
        short8 bt[3];
#pragma unroll
        for (int nt = 0; nt < 3; ++nt)
            bt[nt] = *(const short8*)(Bs + (((9 + s) * 4 + quad) * 48 + nt * 16 + lane15) * 8);
        const int tapq = s * 4 + quad;
        const int kyq  = (tapq * 11) >> 5;             // tapq/3 for 0..11
        const int kxq  = tapq - 3 * kyq;
#pragma unroll
        for (int mt = 0; mt < 2; ++mt) {
            const int arowq = (wv * 2 + mt + kyq) * 18 + (lane15 + kxq);
            const int offs  = (tapq < 9) ? (arowq * 40 + 32) : (ZROW * 40);
            const short8 at = *(const short8*)(x1 + offs);
#pragma unroll
            for (int nt = 0; nt < 3; ++nt)
                acc[mt][nt] = __builtin_amdgcn_mfma_f32_16x16x32_bf16(
                    at, bt[nt], acc[mt][nt], 0, 0, 0);
        }
    }

    // ---- dense1 straight from accumulators; bf16 weights, 1 uint4/segment --
    float a6[6] = {0.f, 0.f, 0.f, 0.f, 0.f, 0.f};
#pragma unroll
    for (int mt = 0; mt < 2; ++mt)
#pragma unroll
        for (int nt = 0; nt < 3; ++nt) {
            const int co = nt * 16 + lane15;
#pragma unroll
            for (int reg = 0; reg < 4; ++reg) {
                const int pixel = (wv * 2 + mt) * 16 + quad * 4 + reg;
                const uint4 wq = *(const uint4*)(d1wb + ((pixel * 48 + co) << 3));
                const float a = fmaxf(acc[mt][nt][reg], 0.f);
                a6[0] = fmaf(a, __uint_as_float(wq.x << 16),          a6[0]);
                a6[1] = fmaf(a, __uint_as_float(wq.x & 0xFFFF0000u),  a6[1]);
                a6[2] = fmaf(a, __uint_as_float(wq.y << 16),          a6[2]);
                a6[3] = fmaf(a, __uint_as_float(wq.y & 0xFFFF0000u),  a6[3]);
                a6[4] = fmaf(a, __uint_as_float(wq.z << 16),          a6[4]);
                a6[5] = fmaf(a, __uint_as_float(wq.z & 0xFFFF0000u),  a6[5]);
            }
        }
    for (int off = 32; off; off >>= 1) {
#pragma unroll
        for (int k = 0; k < 6; ++k) a6[k] += __shfl_down(a6[k], off);
    }
    if (lane == 0) {
#pragma unroll
        for (int k = 0; k < 6; ++k) wsum[wv][k] = a6[k];
    }
    __syncthreads();                                   // B3
    if (t < 6) {
        float s = d1b[t];
#pragma unroll
        for (int w = 0; w < 8; ++w) s += wsum[w][t];
        nodes[n * 6 + t] = fmaxf(s, 0.f);
    }
}

// ---------------------------------------------------------------------------
// Kernel 2: per-node fused edge-MLPs (<=4 incoming, analytic grid adjacency)
// + node MLP + softmax CE.
// node_id(x,y) = ((x&1)+2*(y&1))*1024 + (x>>1)*32 + (y>>1).
// ---------------------------------------------------------------------------
__global__ __launch_bounds__(64) void k_node(
    const float* __restrict__ nodes, const float* __restrict__ lsv,
    const float* __restrict__ we0, const float* __restrict__ be0,
    const float* __restrict__ we1, const float* __restrict__ be1,
    const float* __restrict__ we2, const float* __restrict__ be2,
    const float* __restrict__ we3, const float* __restrict__ be3,
    const float* __restrict__ wn0, const float* __restrict__ bn0,
    const float* __restrict__ wn1, const float* __restrict__ bn1,
    const float* __restrict__ wn2, const float* __restrict__ bn2,
    const float* __restrict__ wn3, const float* __restrict__ bn3,
    const float* __restrict__ wout, const float* __restrict__ bout,
    float* __restrict__ out, int N)
{
    const int n = blockIdx.x * 64 + threadIdx.x;
    if (n >= N) return;
    const int g = n >> 10, cell = n & 1023;
    const int gi = cell >> 5, gj = cell & 31;
    const int gx = (g & 1) + 2 * gi, gy = (g >> 1) + 2 * gj;

    float self6[6];
#pragma unroll
    for (int i = 0; i < 6; ++i) self6[i] = nodes[n * 6 + i];

    float agg[10] = {0.f,0.f,0.f,0.f,0.f,0.f,0.f,0.f,0.f,0.f};
    const int DX[4] = {0, 0, -1, 1};
    const int DY[4] = {-1, 1, 0, 0};
#pragma unroll
    for (int d = 0; d < 4; ++d) {
        const int x = gx + DX[d], y = gy + DY[d];
        if (x >= 0 && x < 64 && y >= 0 && y < 64) {
            const int mid = ((x & 1) + 2 * (y & 1)) * 1024 + (x >> 1) * 32 + (y >> 1);
            float in13[13];
#pragma unroll
            for (int i = 0; i < 6; ++i) in13[i] = nodes[mid * 6 + i];
#pragma unroll
            for (int i = 0; i < 6; ++i) in13[6 + i] = self6[i];
            in13[12] = 1.f;
            float h0[5], h1[5], h2[5], o[10];
            mlp_layer<13, 5>(in13, we0, be0, h0, true);
            mlp_layer<5, 5>(h0, we1, be1, h1, true);
            mlp_layer<5, 5>(h1, we2, be2, h2, true);
            mlp_layer<5, 10>(h2, we3, be3, o, false);
#pragma unroll
            for (int j = 0; j < 10; ++j) agg[j] += o[j];
        }
    }

    float in17[17];
#pragma unroll
    for (int i = 0; i < 6; ++i)  in17[i]     = self6[i];
#pragma unroll
    for (int i = 0; i < 10; ++i) in17[6 + i] = agg[i];
    in17[16] = 1.f;
    float h0[5], h1[5], h2[5], o[10];
    mlp_layer<17, 5>(in17, wn0, bn0, h0, true);
    mlp_layer<5, 5>(h0, wn1, bn1, h1, true);
    mlp_layer<5, 5>(h1, wn2, bn2, h2, true);
    mlp_layer<5, 10>(h2, wn3, bn3, o, false);

    float l0 = bout[0], l1 = bout[1];
#pragma unroll
    for (int i = 0; i < 10; ++i) {
        l0 = fmaf(o[i], wout[i * 2 + 0], l0);
        l1 = fmaf(o[i], wout[i * 2 + 1], l1);
    }
    const float mx  = fmaxf(l0, l1);
    const float e0  = expf(l0 - mx), e1 = expf(l1 - mx);
    const float lse = mx + logf(e0 + e1);
    const float sv  = lsv[n];
    out[n] = -((1.f - sv) * (l0 - lse) + sv * (l1 - lse));
}

// ---------------------------------------------------------------------------
extern "C" void kernel_launch(void* const* d_in, const int* in_sizes, int n_in,
                              void* d_out, int out_size, void* d_ws, size_t ws_size,
                              hipStream_t stream) {
    (void)n_in; (void)ws_size; (void)in_sizes;
    const float* img = (const float*)d_in[0];
    const float* lab = (const float*)d_in[1];
    const float* msk = (const float*)d_in[2];
    const float* w1  = (const float*)d_in[3];
    const float* b1  = (const float*)d_in[4];
    const float* w2  = (const float*)d_in[5];
    const float* b2  = (const float*)d_in[6];
    const float* d1w = (const float*)d_in[7];
    const float* d1b = (const float*)d_in[8];
    const float* we0 = (const float*)d_in[9],  *be0 = (const float*)d_in[10];
    const float* we1 = (const float*)d_in[11], *be1 = (const float*)d_in[12];
    const float* we2 = (const float*)d_in[13], *be2 = (const float*)d_in[14];
    const float* we3 = (const float*)d_in[15], *be3 = (const float*)d_in[16];
    const float* wn0 = (const float*)d_in[17], *bn0 = (const float*)d_in[18];
    const float* wn1 = (const float*)d_in[19], *bn1 = (const float*)d_in[20];
    const float* wn2 = (const float*)d_in[21], *bn2 = (const float*)d_in[22];
    const float* wn3 = (const float*)d_in[23], *bn3 = (const float*)d_in[24];
    const float* wout = (const float*)d_in[25], *bout = (const float*)d_in[26];
    const int N = out_size;              // 4096 nodes

    char* base = (char*)d_ws;
    float* nodes = (float*)base;                             // N*6 floats
    float* lsvb  = (float*)(base + (size_t)N * 6 * 4);       // N floats
    unsigned short* wTbG = (unsigned short*)(base + (size_t)N * 7 * 4);  // 18432
    unsigned short* d1wb = wTbG + NWTB;                      // 98304
    float* out   = (float*)d_out;

    const int prep_n = NWTB + ND1W;
    k_prep<<<(prep_n + 255) / 256, 256, 0, stream>>>(w2, d1w, wTbG, d1wb);
    k_patch<<<N, 512, 0, stream>>>(img, lab, msk, w1, b1, wTbG, b2,
                                   d1wb, d1b, nodes, lsvb);
    k_node<<<(N + 63) / 64, 64, 0, stream>>>(nodes, lsvb,
                                             we0, be0, we1, be1, we2, be2,
                                             we3, be3,
                                             wn0, bn0, wn1, bn1, wn2, bn2,
                                             wn3, bn3, wout, bout, out, N);
}